// Round 6
// baseline (85571.875 us; speedup 1.0000x reference)
//
#include <hip/hip_runtime.h>
#include <hip/hip_bf16.h>
#include <math.h>

#define NN 100000
#define NE 3200000
#define FIN 128
#define HD 64
#define NL 64
#define NC 47
#define RPW 4               // rows per wave (x0 kernel packing)
#define WPB 4               // waves per block
#define RPB (RPW * WPB)

#define SEGSH 13            // source segment = 8192 nodes = 1 MiB bf16 g
#define NSEG 13             // ceil(100000/8192)
#define RBLK 64             // rows owned per layer-block
#define NBLK ((NN + RBLK - 1) / RBLK)     // 1563
#define KPB (NSEG * RBLK)                 // keys per block = 832
#define NKEY (NBLK * KPB)                 // 1,300,416
#define KB ((NKEY + 1023) / 1024)         // scan blocks = 1270

// ---------------- helpers ----------------

__device__ __forceinline__ float bf2f(unsigned short u) {
    union { unsigned int i; float f; } v; v.i = ((unsigned int)u) << 16; return v.f;
}
__device__ __forceinline__ unsigned short f2bf(float f) {
    __hip_bfloat16 h = __float2bfloat16(f);   // RNE
    return *reinterpret_cast<unsigned short*>(&h);
}
__device__ __forceinline__ float fin_at(const void* p, int isf32, size_t i) {
    return isf32 ? ((const float*)p)[i]
                 : __bfloat162float(((const __hip_bfloat16*)p)[i]);
}
__device__ __forceinline__ int edge_at(const void* p, int is64, size_t i) {
    return is64 ? (int)((const long long*)p)[i] : ((const int*)p)[i];
}
// key: block-major, then source-segment, then local dst
__device__ __forceinline__ int edge_key(int s, int d) {
    return (d >> 6) * KPB + (s >> SEGSH) * RBLK + (d & 63);
}

// ---------------- runtime dtype detection ----------------

__global__ void detect_kernel(const void* __restrict__ x, const void* __restrict__ eidx,
                              int* __restrict__ flags) {
    if (threadIdx.x == 0 && blockIdx.x == 0) {
        const unsigned short* u = (const unsigned short*)x;
        int sane = 0;
        for (int i = 0; i < 64; i++) {
            unsigned short v = u[2 * i];
            int e = (v >> 7) & 0xFF;
            if ((v & 0x7FFF) == 0 || (e >= 90 && e <= 141)) sane++;
        }
        flags[0] = (sane >= 48) ? 0 : 1;
        const int* e32 = (const int*)eidx;
        int nz = 0;
        for (int i = 0; i < 64; i++) if (e32[2 * i + 1] != 0) nz++;
        flags[1] = (nz == 0) ? 1 : 0;
    }
}

// ---------------- sorted edge build ----------------

__global__ void key_count(const void* __restrict__ eidx, const int* __restrict__ flags,
                          int* __restrict__ cnt, int* __restrict__ deg) {
    int e = blockIdx.x * blockDim.x + threadIdx.x;
    if (e < NE) {
        int is64 = flags[1];
        int s = edge_at(eidx, is64, (size_t)e);
        int d = edge_at(eidx, is64, (size_t)NE + e);
        atomicAdd(&cnt[edge_key(s, d)], 1);
        atomicAdd(&deg[d], 1);
    }
}

__global__ __launch_bounds__(1024) void scan_reduce(const int* __restrict__ cnt,
                                                    int* __restrict__ bsum) {
    __shared__ int lds[1024];
    int tid = threadIdx.x;
    int i = blockIdx.x * 1024 + tid;
    lds[tid] = (i < NKEY) ? cnt[i] : 0;
    __syncthreads();
    for (int off = 512; off > 0; off >>= 1) {
        if (tid < off) lds[tid] += lds[tid + off];
        __syncthreads();
    }
    if (tid == 0) bsum[blockIdx.x] = lds[0];
}

__global__ __launch_bounds__(1024) void scan_mid(int* __restrict__ bsum, int* __restrict__ total_out) {
    __shared__ int lds[1024];
    __shared__ int base_s;
    int tid = threadIdx.x;
    if (tid == 0) base_s = 0;
    __syncthreads();
    for (int chunk = 0; chunk < KB; chunk += 1024) {
        int i = chunk + tid;
        int v = (i < KB) ? bsum[i] : 0;
        lds[tid] = v;
        __syncthreads();
        for (int off = 1; off < 1024; off <<= 1) {
            int t = (tid >= off) ? lds[tid - off] : 0;
            __syncthreads();
            lds[tid] += t;
            __syncthreads();
        }
        int incl = lds[tid];
        int base = base_s;
        if (i < KB) bsum[i] = base + incl - v;
        __syncthreads();
        if (tid == 1023) base_s = base + incl;
        __syncthreads();
    }
    if (tid == 0) *total_out = base_s;   // == NE
}

__global__ __launch_bounds__(1024) void scan_final(const int* __restrict__ cnt,
                                                   const int* __restrict__ bsum,
                                                   int* __restrict__ keyptr) {
    __shared__ int lds[1024];
    int tid = threadIdx.x;
    int i = blockIdx.x * 1024 + tid;
    int v = (i < NKEY) ? cnt[i] : 0;
    lds[tid] = v;
    __syncthreads();
    for (int off = 1; off < 1024; off <<= 1) {
        int t = (tid >= off) ? lds[tid - off] : 0;
        __syncthreads();
        lds[tid] += t;
        __syncthreads();
    }
    if (i < NKEY) keyptr[i] = bsum[blockIdx.x] + lds[tid] - v;
}

__global__ void dinv_kernel(const int* __restrict__ deg, float* __restrict__ dinv) {
    int i = blockIdx.x * blockDim.x + threadIdx.x;
    if (i < NN) dinv[i] = rsqrtf(1.0f + (float)deg[i]);   // +1 self-loop
}

// col word = src | (local_dst << 20)   (src < 2^17, local_dst < 64)
__global__ void scatter_kernel(const void* __restrict__ eidx, const int* __restrict__ flags,
                               const int* __restrict__ keyptr, int* __restrict__ fill,
                               int* __restrict__ col) {
    int e = blockIdx.x * blockDim.x + threadIdx.x;
    if (e < NE) {
        int is64 = flags[1];
        int s = edge_at(eidx, is64, (size_t)e);
        int d = edge_at(eidx, is64, (size_t)NE + e);
        int key = edge_key(s, d);
        int pos = keyptr[key] + atomicAdd(&fill[key], 1);
        col[pos] = s | ((d & 63) << 20);
    }
}

// ---------------- x0 = relu(x @ W1 + b1); x0 bf16, g0 = dinv*x0 bf16 ----------------

__global__ __launch_bounds__(256) void x0_kernel(const void* __restrict__ x,
                                                 const void* __restrict__ W1,
                                                 const void* __restrict__ b1,
                                                 const int* __restrict__ flags,
                                                 const float* __restrict__ dinv,
                                                 unsigned short* __restrict__ x0b,
                                                 unsigned short* __restrict__ g0) {
    __shared__ float lw[FIN * HD];  // 32 KiB
    int isf = flags[0];
    int tid = threadIdx.x;
    for (int i = tid; i < FIN * HD; i += 256) lw[i] = fin_at(W1, isf, i);
    __syncthreads();
    int wave = tid >> 6, lane = tid & 63;
    int row0 = blockIdx.x * RPB + wave * RPW;
    if (row0 >= NN) return;
    unsigned int pa01, pa23, pb01, pb23;
    {
        unsigned short a0 = f2bf(fin_at(x, isf, (size_t)(row0 + 0) * FIN + lane));
        unsigned short a1 = f2bf(fin_at(x, isf, (size_t)(row0 + 1) * FIN + lane));
        unsigned short a2 = f2bf(fin_at(x, isf, (size_t)(row0 + 2) * FIN + lane));
        unsigned short a3 = f2bf(fin_at(x, isf, (size_t)(row0 + 3) * FIN + lane));
        unsigned short c0 = f2bf(fin_at(x, isf, (size_t)(row0 + 0) * FIN + 64 + lane));
        unsigned short c1 = f2bf(fin_at(x, isf, (size_t)(row0 + 1) * FIN + 64 + lane));
        unsigned short c2 = f2bf(fin_at(x, isf, (size_t)(row0 + 2) * FIN + 64 + lane));
        unsigned short c3 = f2bf(fin_at(x, isf, (size_t)(row0 + 3) * FIN + 64 + lane));
        pa01 = ((unsigned int)a0 << 16) | a1;  pa23 = ((unsigned int)a2 << 16) | a3;
        pb01 = ((unsigned int)c0 << 16) | c1;  pb23 = ((unsigned int)c2 << 16) | c3;
    }
    float bias = fin_at(b1, isf, lane);
    float d0 = bias, d1 = bias, d2 = bias, d3 = bias;
    #pragma unroll 8
    for (int k = 0; k < 64; k++) {
        float w = lw[k * HD + lane];
        unsigned int b01 = __shfl(pa01, k, 64);
        unsigned int b23 = __shfl(pa23, k, 64);
        union { unsigned int i; float f; } f0, f1, f2, f3;
        f0.i = b01 & 0xFFFF0000u; f1.i = b01 << 16;
        f2.i = b23 & 0xFFFF0000u; f3.i = b23 << 16;
        d0 += f0.f * w; d1 += f1.f * w; d2 += f2.f * w; d3 += f3.f * w;
    }
    #pragma unroll 8
    for (int k = 0; k < 64; k++) {
        float w = lw[(64 + k) * HD + lane];
        unsigned int b01 = __shfl(pb01, k, 64);
        unsigned int b23 = __shfl(pb23, k, 64);
        union { unsigned int i; float f; } f0, f1, f2, f3;
        f0.i = b01 & 0xFFFF0000u; f1.i = b01 << 16;
        f2.i = b23 & 0xFFFF0000u; f3.i = b23 << 16;
        d0 += f0.f * w; d1 += f1.f * w; d2 += f2.f * w; d3 += f3.f * w;
    }
    float dd[RPW] = {d0, d1, d2, d3};
    #pragma unroll
    for (int r = 0; r < RPW; r++) {
        int row = row0 + r;
        if (row >= NN) continue;
        float v = fmaxf(dd[r], 0.0f);
        x0b[(size_t)row * HD + lane] = f2bf(v);
        g0[(size_t)row * HD + lane] = f2bf(dinv[row] * v);
    }
}

// ---------------- fused layer, block-cooperative ----------------
// Block b owns rows [b*64, b*64+64). Its edges are contiguous & seg-sorted.
// acc (LDS, fp32) = g[row] (self) + sum g[src]; p = dinv*acc; s = .9p + .1x0;
// h = relu((1-beta)s + beta s@Wl); g_out = dinv*h.

__global__ __launch_bounds__(256) void layer_fused(const int* __restrict__ keyptr,
                                                   const int* __restrict__ col,
                                                   const float* __restrict__ dinv,
                                                   const unsigned short* __restrict__ g_in,
                                                   const unsigned short* __restrict__ x0b,
                                                   unsigned short* __restrict__ g_out,
                                                   const void* __restrict__ convW, int layer,
                                                   const int* __restrict__ flags, float beta) {
    __shared__ float lw[HD * HD];    // 16 KiB
    __shared__ float acc[RBLK * HD]; // 16 KiB
    int isf = flags[0];
    size_t wbase = (size_t)layer * HD * HD;
    int tid = threadIdx.x;
    int row0 = blockIdx.x * RBLK;
    #pragma unroll
    for (int i = tid; i < HD * HD; i += 256) lw[i] = fin_at(convW, isf, wbase + i);
    // init acc with self-loop contribution g[row]
    #pragma unroll
    for (int i = tid; i < RBLK * HD; i += 256) {
        int row = row0 + (i >> 6);
        acc[i] = (row < NN) ? bf2f(g_in[(size_t)row * HD + (i & 63)]) : 0.0f;
    }
    __syncthreads();

    int wave = tid >> 6, lane = tid & 63;
    int S = keyptr[blockIdx.x * KPB];
    int E = keyptr[(blockIdx.x + 1) * KPB];   // keyptr[NKEY] == NE for last block

    // waves take 64-edge chunks round-robin -> all 4 waves sweep segments together
    for (int base = S + wave * 64; base < E; base += 256) {
        int idx = base + lane;
        int cc = (idx < E) ? col[idx] : 0;
        int n = min(64, E - base);
        int j = 0;
        for (; j + 8 <= n; j += 8) {
            int v0 = __shfl(cc, j, 64),     v1 = __shfl(cc, j + 1, 64);
            int v2 = __shfl(cc, j + 2, 64), v3 = __shfl(cc, j + 3, 64);
            int v4 = __shfl(cc, j + 4, 64), v5 = __shfl(cc, j + 5, 64);
            int v6 = __shfl(cc, j + 6, 64), v7 = __shfl(cc, j + 7, 64);
            unsigned short u0 = g_in[(size_t)((v0 & 0xFFFFF) << 6) + lane];
            unsigned short u1 = g_in[(size_t)((v1 & 0xFFFFF) << 6) + lane];
            unsigned short u2 = g_in[(size_t)((v2 & 0xFFFFF) << 6) + lane];
            unsigned short u3 = g_in[(size_t)((v3 & 0xFFFFF) << 6) + lane];
            unsigned short u4 = g_in[(size_t)((v4 & 0xFFFFF) << 6) + lane];
            unsigned short u5 = g_in[(size_t)((v5 & 0xFFFFF) << 6) + lane];
            unsigned short u6 = g_in[(size_t)((v6 & 0xFFFFF) << 6) + lane];
            unsigned short u7 = g_in[(size_t)((v7 & 0xFFFFF) << 6) + lane];
            atomicAdd(&acc[((v0 >> 20) << 6) + lane], bf2f(u0));
            atomicAdd(&acc[((v1 >> 20) << 6) + lane], bf2f(u1));
            atomicAdd(&acc[((v2 >> 20) << 6) + lane], bf2f(u2));
            atomicAdd(&acc[((v3 >> 20) << 6) + lane], bf2f(u3));
            atomicAdd(&acc[((v4 >> 20) << 6) + lane], bf2f(u4));
            atomicAdd(&acc[((v5 >> 20) << 6) + lane], bf2f(u5));
            atomicAdd(&acc[((v6 >> 20) << 6) + lane], bf2f(u6));
            atomicAdd(&acc[((v7 >> 20) << 6) + lane], bf2f(u7));
        }
        for (; j < n; j++) {
            int v = __shfl(cc, j, 64);
            unsigned short u = g_in[(size_t)((v & 0xFFFFF) << 6) + lane];
            atomicAdd(&acc[((v >> 20) << 6) + lane], bf2f(u));
        }
    }
    __syncthreads();

    // epilogue: each wave handles 16 rows in 4 packed groups of 4
    float omb = 1.0f - beta;
    for (int grp = 0; grp < 4; grp++) {
        int lr0 = wave * 16 + grp * 4;
        float sacc[4];
        float dsc[4];
        #pragma unroll
        for (int r = 0; r < 4; r++) {
            int row = row0 + lr0 + r;
            if (row >= NN) { sacc[r] = 0.0f; dsc[r] = 1.0f; continue; }
            float di = dinv[row];
            dsc[r] = di;
            float a = acc[(lr0 + r) * HD + lane];
            sacc[r] = 0.9f * (di * a) + 0.1f * bf2f(x0b[(size_t)row * HD + lane]);
        }
        unsigned int p01 = ((unsigned int)f2bf(sacc[0]) << 16) | f2bf(sacc[1]);
        unsigned int p23 = ((unsigned int)f2bf(sacc[2]) << 16) | f2bf(sacc[3]);
        float d0 = 0.0f, d1 = 0.0f, d2 = 0.0f, d3 = 0.0f;
        #pragma unroll 8
        for (int k = 0; k < 64; k++) {
            float w = lw[k * HD + lane];
            unsigned int b01 = __shfl(p01, k, 64);
            unsigned int b23 = __shfl(p23, k, 64);
            union { unsigned int i; float f; } f0, f1, f2, f3;
            f0.i = b01 & 0xFFFF0000u; f1.i = b01 << 16;
            f2.i = b23 & 0xFFFF0000u; f3.i = b23 << 16;
            d0 += f0.f * w; d1 += f1.f * w;
            d2 += f2.f * w; d3 += f3.f * w;
        }
        float dd[4] = {d0, d1, d2, d3};
        #pragma unroll
        for (int r = 0; r < 4; r++) {
            int row = row0 + lr0 + r;
            if (row >= NN) continue;
            float res = omb * sacc[r] + beta * dd[r];
            g_out[(size_t)row * HD + lane] = f2bf(dsc[r] * fmaxf(res, 0.0f));
        }
    }
}

// ---------------- out = log_softmax(h @ W2 + b2), h = g/dinv ----------------

__global__ __launch_bounds__(256) void out_kernel(const unsigned short* __restrict__ g,
                                                  const float* __restrict__ dinv,
                                                  const void* __restrict__ W2,
                                                  const void* __restrict__ b2,
                                                  const int* __restrict__ flags,
                                                  void* __restrict__ out) {
    __shared__ float lw[HD * 64];
    int isf = flags[0];
    int tid = threadIdx.x;
    for (int i = tid; i < HD * 64; i += 256) {
        int k = i >> 6, j = i & 63;
        lw[i] = (j < NC) ? fin_at(W2, isf, (size_t)k * NC + j) : 0.0f;
    }
    __syncthreads();
    int row = blockIdx.x * 4 + (tid >> 6);
    int lane = tid & 63;
    if (row >= NN) return;
    float hv = bf2f(g[(size_t)row * HD + lane]) / dinv[row];
    float acc = (lane < NC) ? fin_at(b2, isf, lane) : 0.0f;
    #pragma unroll 8
    for (int k = 0; k < 64; k++) {
        float hk = __shfl(hv, k, 64);
        acc += hk * lw[k * 64 + lane];
    }
    float mv = (lane < NC) ? acc : -1e30f;
    for (int off = 32; off > 0; off >>= 1) mv = fmaxf(mv, __shfl_xor(mv, off, 64));
    float ex = (lane < NC) ? expf(acc - mv) : 0.0f;
    float se = ex;
    for (int off = 32; off > 0; off >>= 1) se += __shfl_xor(se, off, 64);
    float res = acc - mv - logf(se);
    if (lane < NC) {
        size_t oi = (size_t)row * NC + lane;
        if (isf) ((float*)out)[oi] = res;
        else     ((__hip_bfloat16*)out)[oi] = __float2bfloat16(res);
    }
}

// ---------------- host ----------------

static inline size_t align256(size_t x) { return (x + 255) & ~(size_t)255; }

extern "C" void kernel_launch(void* const* d_in, const int* in_sizes, int n_in,
                              void* d_out, int out_size, void* d_ws, size_t ws_size,
                              hipStream_t stream) {
    const void* x     = d_in[0];
    const void* eidx  = d_in[1];
    const void* W1    = d_in[2];
    const void* b1    = d_in[3];
    const void* convW = d_in[4];
    const void* W2    = d_in[5];
    const void* b2    = d_in[6];

    char* p = (char*)d_ws;
    size_t off = 0;
    auto alloc = [&](size_t bytes) { void* r = p + off; off += align256(bytes); return r; };
    int*            flags   = (int*)alloc(256);
    int*            cnt     = (int*)alloc((size_t)NKEY * 4);
    int*            fill    = (int*)alloc((size_t)NKEY * 4);
    int*            keyptr  = (int*)alloc((size_t)(NKEY + 1) * 4);
    int*            bsum    = (int*)alloc((size_t)KB * 4);
    int*            deg     = (int*)alloc((size_t)NN * 4);
    float*          dinv    = (float*)alloc((size_t)NN * 4);
    int*            col     = (int*)alloc((size_t)NE * 4);
    unsigned short* x0b     = (unsigned short*)alloc((size_t)NN * HD * 2);
    unsigned short* hA      = (unsigned short*)alloc((size_t)NN * HD * 2);
    unsigned short* hB      = (unsigned short*)alloc((size_t)NN * HD * 2);

    detect_kernel<<<1, 64, 0, stream>>>(x, eidx, flags);

    hipMemsetAsync(cnt, 0, (size_t)NKEY * 4, stream);
    hipMemsetAsync(fill, 0, (size_t)NKEY * 4, stream);
    hipMemsetAsync(deg, 0, (size_t)NN * 4, stream);
    key_count<<<(NE + 255) / 256, 256, 0, stream>>>(eidx, flags, cnt, deg);
    scan_reduce<<<KB, 1024, 0, stream>>>(cnt, bsum);
    scan_mid<<<1, 1024, 0, stream>>>(bsum, keyptr + NKEY);
    scan_final<<<KB, 1024, 0, stream>>>(cnt, bsum, keyptr);
    dinv_kernel<<<(NN + 255) / 256, 256, 0, stream>>>(deg, dinv);
    scatter_kernel<<<(NE + 255) / 256, 256, 0, stream>>>(eidx, flags, keyptr, fill, col);

    x0_kernel<<<(NN + RPB - 1) / RPB, 256, 0, stream>>>(x, W1, b1, flags, dinv, x0b, hA);

    unsigned short* gin = hA;
    unsigned short* gout = hB;
    for (int l = 0; l < NL; l++) {
        float beta = logf(0.5f / (float)(l + 1) + 1.0f);
        layer_fused<<<NBLK, 256, 0, stream>>>(keyptr, col, dinv, gin, x0b, gout,
                                              convW, l, flags, beta);
        unsigned short* t = gin; gin = gout; gout = t;
    }
    out_kernel<<<(NN + 3) / 4, 256, 0, stream>>>(gin, dinv, W2, b2, flags, (void*)d_out);
}

// Round 7
// 7539.574 us; speedup vs baseline: 11.3497x; 11.3497x over previous
//
#include <hip/hip_runtime.h>
#include <hip/hip_bf16.h>
#include <math.h>

#define NN 100000
#define NE 3200000
#define FIN 128
#define HD 64
#define NL 64
#define NC 47
#define RPW 4               // rows per wave
#define WPB 4               // waves per block
#define RPB (RPW * WPB)     // rows per block = 16

#define SEGSH 13            // source segment = 8192 nodes (1 MiB of bf16 g)
#define NSEG 13             // ceil(100000 / 8192)
#define NKEY (NN * NSEG)    // 1.3M (dst, seg) keys
#define KB ((NKEY + 1023) / 1024)   // scan blocks

// ---------------- helpers ----------------

__device__ __forceinline__ float bf2f(unsigned short u) {
    union { unsigned int i; float f; } v; v.i = ((unsigned int)u) << 16; return v.f;
}
__device__ __forceinline__ unsigned short f2bf(float f) {
    __hip_bfloat16 h = __float2bfloat16(f);   // RNE
    return *reinterpret_cast<unsigned short*>(&h);
}
__device__ __forceinline__ float fin_at(const void* p, int isf32, size_t i) {
    return isf32 ? ((const float*)p)[i]
                 : __bfloat162float(((const __hip_bfloat16*)p)[i]);
}
__device__ __forceinline__ int edge_at(const void* p, int is64, size_t i) {
    return is64 ? (int)((const long long*)p)[i] : ((const int*)p)[i];
}

// ---------------- runtime dtype detection ----------------
// flags[0]: 1 = float inputs are fp32, 0 = bf16
// flags[1]: 1 = edge_index is int64, 0 = int32

__global__ void detect_kernel(const void* __restrict__ x, const void* __restrict__ eidx,
                              int* __restrict__ flags) {
    if (threadIdx.x == 0 && blockIdx.x == 0) {
        const unsigned short* u = (const unsigned short*)x;
        int sane = 0;
        for (int i = 0; i < 64; i++) {
            unsigned short v = u[2 * i];
            int e = (v >> 7) & 0xFF;
            if ((v & 0x7FFF) == 0 || (e >= 90 && e <= 141)) sane++;
        }
        flags[0] = (sane >= 48) ? 0 : 1;
        const int* e32 = (const int*)eidx;
        int nz = 0;
        for (int i = 0; i < 64; i++) if (e32[2 * i + 1] != 0) nz++;
        flags[1] = (nz == 0) ? 1 : 0;
    }
}

// ---------------- segmented-CSR build (round-5 layout: key = dst*NSEG + seg) ----

__global__ void key_count(const void* __restrict__ eidx, const int* __restrict__ flags,
                          int* __restrict__ cnt) {
    int e = blockIdx.x * blockDim.x + threadIdx.x;
    if (e < NE) {
        int is64 = flags[1];
        int s = edge_at(eidx, is64, (size_t)e);
        int d = edge_at(eidx, is64, (size_t)NE + e);
        atomicAdd(&cnt[d * NSEG + (s >> SEGSH)], 1);
    }
}

__global__ __launch_bounds__(1024) void scan_reduce(const int* __restrict__ cnt,
                                                    int* __restrict__ bsum) {
    __shared__ int lds[1024];
    int tid = threadIdx.x;
    int i = blockIdx.x * 1024 + tid;
    lds[tid] = (i < NKEY) ? cnt[i] : 0;
    __syncthreads();
    for (int off = 512; off > 0; off >>= 1) {
        if (tid < off) lds[tid] += lds[tid + off];
        __syncthreads();
    }
    if (tid == 0) bsum[blockIdx.x] = lds[0];
}

__global__ __launch_bounds__(1024) void scan_mid(int* __restrict__ bsum, int* __restrict__ total_out) {
    __shared__ int lds[1024];
    __shared__ int base_s;
    int tid = threadIdx.x;
    if (tid == 0) base_s = 0;
    __syncthreads();
    for (int chunk = 0; chunk < KB; chunk += 1024) {
        int i = chunk + tid;
        int v = (i < KB) ? bsum[i] : 0;
        lds[tid] = v;
        __syncthreads();
        for (int off = 1; off < 1024; off <<= 1) {
            int t = (tid >= off) ? lds[tid - off] : 0;
            __syncthreads();
            lds[tid] += t;
            __syncthreads();
        }
        int incl = lds[tid];
        int base = base_s;
        if (i < KB) bsum[i] = base + incl - v;
        __syncthreads();
        if (tid == 1023) base_s = base + incl;
        __syncthreads();
    }
    if (tid == 0) *total_out = base_s;   // == NE
}

__global__ __launch_bounds__(1024) void scan_final(const int* __restrict__ cnt,
                                                   const int* __restrict__ bsum,
                                                   int* __restrict__ keyptr) {
    __shared__ int lds[1024];
    int tid = threadIdx.x;
    int i = blockIdx.x * 1024 + tid;
    int v = (i < NKEY) ? cnt[i] : 0;
    lds[tid] = v;
    __syncthreads();
    for (int off = 1; off < 1024; off <<= 1) {
        int t = (tid >= off) ? lds[tid - off] : 0;
        __syncthreads();
        lds[tid] += t;
        __syncthreads();
    }
    if (i < NKEY) keyptr[i] = bsum[blockIdx.x] + lds[tid] - v;
}

__global__ void dinv_kernel(const int* __restrict__ keyptr, float* __restrict__ dinv) {
    int i = blockIdx.x * blockDim.x + threadIdx.x;
    if (i < NN) {
        int deg = keyptr[(i + 1) * NSEG] - keyptr[i * NSEG];
        dinv[i] = rsqrtf(1.0f + (float)deg);   // +1 self-loop
    }
}

__global__ void scatter_kernel(const void* __restrict__ eidx, const int* __restrict__ flags,
                               const int* __restrict__ keyptr, int* __restrict__ fill,
                               int* __restrict__ col) {
    int e = blockIdx.x * blockDim.x + threadIdx.x;
    if (e < NE) {
        int is64 = flags[1];
        int s = edge_at(eidx, is64, (size_t)e);
        int d = edge_at(eidx, is64, (size_t)NE + e);
        int key = d * NSEG + (s >> SEGSH);
        int pos = keyptr[key] + atomicAdd(&fill[key], 1);
        col[pos] = s;
    }
}

// ---------------- x0 = relu(x @ W1 + b1); x0 bf16, g0 = dinv*x0 bf16 ----------------

__global__ __launch_bounds__(256) void x0_kernel(const void* __restrict__ x,
                                                 const void* __restrict__ W1,
                                                 const void* __restrict__ b1,
                                                 const int* __restrict__ flags,
                                                 const float* __restrict__ dinv,
                                                 unsigned short* __restrict__ x0b,
                                                 unsigned short* __restrict__ g0) {
    __shared__ float lw[FIN * HD];  // 32 KiB
    int isf = flags[0];
    int tid = threadIdx.x;
    for (int i = tid; i < FIN * HD; i += 256) lw[i] = fin_at(W1, isf, i);
    __syncthreads();
    int wave = tid >> 6, lane = tid & 63;
    int row0 = blockIdx.x * RPB + wave * RPW;
    if (row0 >= NN) return;
    unsigned int pa01, pa23, pb01, pb23;
    {
        unsigned short a0 = f2bf(fin_at(x, isf, (size_t)(row0 + 0) * FIN + lane));
        unsigned short a1 = f2bf(fin_at(x, isf, (size_t)(row0 + 1) * FIN + lane));
        unsigned short a2 = f2bf(fin_at(x, isf, (size_t)(row0 + 2) * FIN + lane));
        unsigned short a3 = f2bf(fin_at(x, isf, (size_t)(row0 + 3) * FIN + lane));
        unsigned short c0 = f2bf(fin_at(x, isf, (size_t)(row0 + 0) * FIN + 64 + lane));
        unsigned short c1 = f2bf(fin_at(x, isf, (size_t)(row0 + 1) * FIN + 64 + lane));
        unsigned short c2 = f2bf(fin_at(x, isf, (size_t)(row0 + 2) * FIN + 64 + lane));
        unsigned short c3 = f2bf(fin_at(x, isf, (size_t)(row0 + 3) * FIN + 64 + lane));
        pa01 = ((unsigned int)a0 << 16) | a1;  pa23 = ((unsigned int)a2 << 16) | a3;
        pb01 = ((unsigned int)c0 << 16) | c1;  pb23 = ((unsigned int)c2 << 16) | c3;
    }
    float bias = fin_at(b1, isf, lane);
    float d0 = bias, d1 = bias, d2 = bias, d3 = bias;
    #pragma unroll 8
    for (int k = 0; k < 64; k++) {
        float w = lw[k * HD + lane];
        unsigned int b01 = __shfl(pa01, k, 64);
        unsigned int b23 = __shfl(pa23, k, 64);
        union { unsigned int i; float f; } f0, f1, f2, f3;
        f0.i = b01 & 0xFFFF0000u; f1.i = b01 << 16;
        f2.i = b23 & 0xFFFF0000u; f3.i = b23 << 16;
        d0 += f0.f * w; d1 += f1.f * w; d2 += f2.f * w; d3 += f3.f * w;
    }
    #pragma unroll 8
    for (int k = 0; k < 64; k++) {
        float w = lw[(64 + k) * HD + lane];
        unsigned int b01 = __shfl(pb01, k, 64);
        unsigned int b23 = __shfl(pb23, k, 64);
        union { unsigned int i; float f; } f0, f1, f2, f3;
        f0.i = b01 & 0xFFFF0000u; f1.i = b01 << 16;
        f2.i = b23 & 0xFFFF0000u; f3.i = b23 << 16;
        d0 += f0.f * w; d1 += f1.f * w; d2 += f2.f * w; d3 += f3.f * w;
    }
    float dd[RPW] = {d0, d1, d2, d3};
    #pragma unroll
    for (int r = 0; r < RPW; r++) {
        int row = row0 + r;
        if (row >= NN) continue;
        float v = fmaxf(dd[r], 0.0f);
        x0b[(size_t)row * HD + lane] = f2bf(v);
        g0[(size_t)row * HD + lane] = f2bf(dinv[row] * v);
    }
}

// ---------------- fused layer ----------------
// Wave-uniform row processing: col[j] is wave-uniform -> scalar (s_load) path;
// gather is saddr-form global_load_ushort with zero per-edge address VALU.
// p[d] = dinv[d]*(sum g[s] + g[d]); s = .9p + .1x0; h = relu((1-b)s + b s@Wl);
// g_out = dinv*h.

__global__ __launch_bounds__(256, 8) void layer_fused(const int* __restrict__ keyptr,
                                                      const int* __restrict__ col,
                                                      const float* __restrict__ dinv,
                                                      const unsigned short* __restrict__ g_in,
                                                      const unsigned short* __restrict__ x0b,
                                                      unsigned short* __restrict__ g_out,
                                                      const void* __restrict__ convW, int layer,
                                                      const int* __restrict__ flags, float beta) {
    __shared__ float lw[HD * HD];  // 16 KiB
    int isf = flags[0];
    size_t wbase = (size_t)layer * HD * HD;
    int tid = threadIdx.x;
    for (int i = tid; i < HD * HD; i += 256) lw[i] = fin_at(convW, isf, wbase + i);
    __syncthreads();

    // force wave-uniform SGPR value so col/keyptr loads become scalar loads
    int wave = __builtin_amdgcn_readfirstlane(tid >> 6);
    int lane = tid & 63;
    int row0 = blockIdx.x * RPB + wave * RPW;

    float sacc[RPW];
    float dsc[RPW];
    #pragma unroll
    for (int r = 0; r < RPW; r++) {
        int row = row0 + r;
        if (row >= NN) { sacc[r] = 0.0f; dsc[r] = 1.0f; continue; }
        float a = bf2f(g_in[((size_t)row << 6) + lane]);  // self-loop g[d]
        int j = keyptr[row * NSEG];
        int end = keyptr[(row + 1) * NSEG];
        for (; j + 8 <= end; j += 8) {
            int c0 = col[j + 0], c1 = col[j + 1], c2 = col[j + 2], c3 = col[j + 3];
            int c4 = col[j + 4], c5 = col[j + 5], c6 = col[j + 6], c7 = col[j + 7];
            unsigned short u0 = g_in[((size_t)c0 << 6) + lane];
            unsigned short u1 = g_in[((size_t)c1 << 6) + lane];
            unsigned short u2 = g_in[((size_t)c2 << 6) + lane];
            unsigned short u3 = g_in[((size_t)c3 << 6) + lane];
            unsigned short u4 = g_in[((size_t)c4 << 6) + lane];
            unsigned short u5 = g_in[((size_t)c5 << 6) + lane];
            unsigned short u6 = g_in[((size_t)c6 << 6) + lane];
            unsigned short u7 = g_in[((size_t)c7 << 6) + lane];
            a += bf2f(u0); a += bf2f(u1); a += bf2f(u2); a += bf2f(u3);
            a += bf2f(u4); a += bf2f(u5); a += bf2f(u6); a += bf2f(u7);
        }
        for (; j < end; j++) {
            int c = col[j];
            a += bf2f(g_in[((size_t)c << 6) + lane]);
        }
        float di = dinv[row];
        dsc[r] = di;
        sacc[r] = 0.9f * (di * a) + 0.1f * bf2f(x0b[((size_t)row << 6) + lane]);
    }

    // dense: d = s @ Wl ; s packed 2-rows-per-dword bf16, broadcast via shfl
    unsigned int p01 = ((unsigned int)f2bf(sacc[0]) << 16) | f2bf(sacc[1]);
    unsigned int p23 = ((unsigned int)f2bf(sacc[2]) << 16) | f2bf(sacc[3]);
    float d0 = 0.0f, d1 = 0.0f, d2 = 0.0f, d3 = 0.0f;
    #pragma unroll 8
    for (int k = 0; k < 64; k++) {
        float w = lw[k * HD + lane];
        unsigned int b01 = __shfl(p01, k, 64);
        unsigned int b23 = __shfl(p23, k, 64);
        union { unsigned int i; float f; } f0, f1, f2, f3;
        f0.i = b01 & 0xFFFF0000u; f1.i = b01 << 16;
        f2.i = b23 & 0xFFFF0000u; f3.i = b23 << 16;
        d0 += f0.f * w; d1 += f1.f * w;
        d2 += f2.f * w; d3 += f3.f * w;
    }

    float dd[RPW] = {d0, d1, d2, d3};
    float omb = 1.0f - beta;
    #pragma unroll
    for (int r = 0; r < RPW; r++) {
        int row = row0 + r;
        if (row >= NN) continue;
        float res = omb * sacc[r] + beta * dd[r];
        g_out[((size_t)row << 6) + lane] = f2bf(dsc[r] * fmaxf(res, 0.0f));
    }
}

// ---------------- out = log_softmax(h @ W2 + b2), h = g/dinv ----------------

__global__ __launch_bounds__(256) void out_kernel(const unsigned short* __restrict__ g,
                                                  const float* __restrict__ dinv,
                                                  const void* __restrict__ W2,
                                                  const void* __restrict__ b2,
                                                  const int* __restrict__ flags,
                                                  void* __restrict__ out) {
    __shared__ float lw[HD * 64];
    int isf = flags[0];
    int tid = threadIdx.x;
    for (int i = tid; i < HD * 64; i += 256) {
        int k = i >> 6, j = i & 63;
        lw[i] = (j < NC) ? fin_at(W2, isf, (size_t)k * NC + j) : 0.0f;
    }
    __syncthreads();
    int row = blockIdx.x * 4 + (tid >> 6);
    int lane = tid & 63;
    if (row >= NN) return;
    float hv = bf2f(g[(size_t)row * HD + lane]) / dinv[row];
    float acc = (lane < NC) ? fin_at(b2, isf, lane) : 0.0f;
    #pragma unroll 8
    for (int k = 0; k < 64; k++) {
        float hk = __shfl(hv, k, 64);
        acc += hk * lw[k * 64 + lane];
    }
    float mv = (lane < NC) ? acc : -1e30f;
    for (int off = 32; off > 0; off >>= 1) mv = fmaxf(mv, __shfl_xor(mv, off, 64));
    float ex = (lane < NC) ? expf(acc - mv) : 0.0f;
    float se = ex;
    for (int off = 32; off > 0; off >>= 1) se += __shfl_xor(se, off, 64);
    float res = acc - mv - logf(se);
    if (lane < NC) {
        size_t oi = (size_t)row * NC + lane;
        if (isf) ((float*)out)[oi] = res;
        else     ((__hip_bfloat16*)out)[oi] = __float2bfloat16(res);
    }
}

// ---------------- host ----------------

static inline size_t align256(size_t x) { return (x + 255) & ~(size_t)255; }

extern "C" void kernel_launch(void* const* d_in, const int* in_sizes, int n_in,
                              void* d_out, int out_size, void* d_ws, size_t ws_size,
                              hipStream_t stream) {
    const void* x     = d_in[0];
    const void* eidx  = d_in[1];
    const void* W1    = d_in[2];
    const void* b1    = d_in[3];
    const void* convW = d_in[4];
    const void* W2    = d_in[5];
    const void* b2    = d_in[6];

    char* p = (char*)d_ws;
    size_t off = 0;
    auto alloc = [&](size_t bytes) { void* r = p + off; off += align256(bytes); return r; };
    int*            flags   = (int*)alloc(256);
    int*            cnt     = (int*)alloc((size_t)NKEY * 4);
    int*            fill    = (int*)alloc((size_t)NKEY * 4);
    int*            keyptr  = (int*)alloc((size_t)(NKEY + 1) * 4);
    int*            bsum    = (int*)alloc((size_t)KB * 4);
    float*          dinv    = (float*)alloc((size_t)NN * 4);
    int*            col     = (int*)alloc((size_t)NE * 4);
    unsigned short* x0b     = (unsigned short*)alloc((size_t)NN * HD * 2);
    unsigned short* hA      = (unsigned short*)alloc((size_t)NN * HD * 2);
    unsigned short* hB      = (unsigned short*)alloc((size_t)NN * HD * 2);

    detect_kernel<<<1, 64, 0, stream>>>(x, eidx, flags);

    hipMemsetAsync(cnt, 0, (size_t)NKEY * 4, stream);
    hipMemsetAsync(fill, 0, (size_t)NKEY * 4, stream);
    key_count<<<(NE + 255) / 256, 256, 0, stream>>>(eidx, flags, cnt);
    scan_reduce<<<KB, 1024, 0, stream>>>(cnt, bsum);
    scan_mid<<<1, 1024, 0, stream>>>(bsum, keyptr + NKEY);
    scan_final<<<KB, 1024, 0, stream>>>(cnt, bsum, keyptr);
    dinv_kernel<<<(NN + 255) / 256, 256, 0, stream>>>(keyptr, dinv);
    scatter_kernel<<<(NE + 255) / 256, 256, 0, stream>>>(eidx, flags, keyptr, fill, col);

    int fb = (NN + RPB - 1) / RPB;  // 6250 blocks
    x0_kernel<<<fb, 256, 0, stream>>>(x, W1, b1, flags, dinv, x0b, hA);

    unsigned short* gin = hA;
    unsigned short* gout = hB;
    for (int l = 0; l < NL; l++) {
        float beta = logf(0.5f / (float)(l + 1) + 1.0f);
        layer_fused<<<fb, 256, 0, stream>>>(keyptr, col, dinv, gin, x0b, gout,
                                            convW, l, flags, beta);
        unsigned short* t = gin; gin = gout; gout = t;
    }
    out_kernel<<<(NN + 3) / 4, 256, 0, stream>>>(gin, dinv, W2, b2, flags, (void*)d_out);
}